// Round 1
// baseline (402.861 us; speedup 1.0000x reference)
//
#include <hip/hip_runtime.h>

#define KS    11
#define HH    512
#define WW    512
#define OUTD  502          // HH - KS + 1
#define OH    67           // output rows per band
#define ROWS  77           // OH + KS - 1, = 7*11
#define NB    8            // 8*67 = 536 >= 502
#define NIMG  96           // N*C = 32*3
#define PADW  524          // 512 + pad for horizontal reads up to c+11

// Streaming separable SSIM, sum/difference form:
//  s = x+y, d = x-y staged in LDS (double-buffered, 1 barrier/row).
//  Only 4 convolved quantities {s, d, s^2, d^2} instead of 5:
//    4 mu_x mu_y        = ms^2 - md^2
//    2(mu_x^2+mu_y^2)   = ms^2 + md^2
//    4 conv(xy)         = Sss - Sdd
//    2(conv x^2 + y^2)  = Sss + Sdd
//  SSIM ratio: factors of 2/4 cancel against doubled constants.
//  Grid: 96 images x 8 bands = 768 blocks = exactly 3 blocks/CU on 256 CUs,
//  __launch_bounds__(256,3) guarantees all blocks co-resident (no tail).
__global__ __launch_bounds__(256, 3)
void ssim_main(const float* __restrict__ xg, const float* __restrict__ yg,
               const float* __restrict__ win, double* __restrict__ acc_out)
{
    __shared__ float shs[2][PADW];   // s = x+y
    __shared__ float shd[2][PADW];   // d = x-y
    __shared__ float wsums[4];

    const int tid  = threadIdx.x;
    const int img  = blockIdx.x % NIMG;
    const int band = blockIdx.x / NIMG;
    const int row0 = band * OH;
    const int c0   = 2 * tid;

    // Recover 1D gaussian from the (normalized, rank-1) 2D window: row sums.
    float g[KS];
    #pragma unroll
    for (int i = 0; i < KS; i++) {
        float s = 0.f;
        #pragma unroll
        for (int j = 0; j < KS; j++) s += win[i * KS + j];
        g[i] = s;
    }

    // Zero the LDS pad (cols 512..PADW-1); only feeds invalid outputs but must be finite.
    if (tid < (PADW - WW)) {
        shs[0][WW + tid] = 0.f; shs[1][WW + tid] = 0.f;
        shd[0][WW + tid] = 0.f; shd[1][WW + tid] = 0.f;
    }

    const float* xi = xg + (size_t)img * HH * WW;
    const float* yi = yg + (size_t)img * HH * WW;

    // rotating vertical accumulators [quantity][col][slot]; q: 0=s 1=d 2=s2 3=d2
    float acc[4][2][KS];
    #pragma unroll
    for (int q = 0; q < 4; q++)
        #pragma unroll
        for (int c = 0; c < 2; c++)
            #pragma unroll
            for (int s = 0; s < KS; s++) acc[q][c][s] = 0.f;

    float ssum = 0.f;

    const float C1x2 = 0.0002f;  // 2*(0.01)^2
    const float C2x2 = 0.0018f;  // 2*(0.03)^2

    // prologue: row 0 -> buf0 (as s,d), prefetch row 1 into regs (as s,d)
    float2 pfs, pfd;
    {
        int gr = row0; if (gr > HH - 1) gr = HH - 1;
        float2 ax = *(const float2*)&xi[(size_t)gr * WW + c0];
        float2 ay = *(const float2*)&yi[(size_t)gr * WW + c0];
        shs[0][c0] = ax.x + ay.x; shs[0][c0 + 1] = ax.y + ay.y;
        shd[0][c0] = ax.x - ay.x; shd[0][c0 + 1] = ax.y - ay.y;
        gr = row0 + 1; if (gr > HH - 1) gr = HH - 1;
        ax = *(const float2*)&xi[(size_t)gr * WW + c0];
        ay = *(const float2*)&yi[(size_t)gr * WW + c0];
        pfs = make_float2(ax.x + ay.x, ax.y + ay.y);
        pfd = make_float2(ax.x - ay.x, ax.y - ay.y);
    }
    __syncthreads();

    #pragma unroll 1
    for (int rb = 0; rb < ROWS / KS; rb++) {
        #pragma unroll
        for (int rr = 0; rr < KS; rr++) {
            const int r = rb * KS + rr;

            // ---- read 12 s / 12 d for this row from LDS (b64, contiguous) ----
            const float* sb = shs[r & 1];
            const float* db = shd[r & 1];
            float sv[12], dv[12];
            #pragma unroll
            for (int k = 0; k < 6; k++) {
                float2 a = *(const float2*)&sb[c0 + 2 * k];
                float2 b = *(const float2*)&db[c0 + 2 * k];
                sv[2 * k] = a.x; sv[2 * k + 1] = a.y;
                dv[2 * k] = b.x; dv[2 * k + 1] = b.y;
            }

            // ---- write prefetched row r+1 into the other buffer; prefetch r+2 ----
            if (r + 1 < ROWS) {
                float* sw = shs[(r + 1) & 1];
                float* dw = shd[(r + 1) & 1];
                sw[c0] = pfs.x; sw[c0 + 1] = pfs.y;
                dw[c0] = pfd.x; dw[c0 + 1] = pfd.y;
            }
            if (r + 2 < ROWS) {
                int gr = row0 + r + 2; if (gr > HH - 1) gr = HH - 1;
                float2 ax = *(const float2*)&xi[(size_t)gr * WW + c0];
                float2 ay = *(const float2*)&yi[(size_t)gr * WW + c0];
                pfs = make_float2(ax.x + ay.x, ax.y + ay.y);
                pfd = make_float2(ax.x - ay.x, ax.y - ay.y);
            }

            // ---- horizontal 11-tap conv, 2 cols x 4 quantities ----
            // squares computed with a rolling pair (ts,td) so only 2 transient
            // regs are live instead of a 24-element array (keeps us < 170 VGPR).
            float h0a = 0.f, h0b = 0.f, h1a = 0.f, h1b = 0.f;
            float h2a = 0.f, h2b = 0.f, h3a = 0.f, h3b = 0.f;
            float ts = sv[0] * sv[0];
            float td = dv[0] * dv[0];
            #pragma unroll
            for (int j = 0; j < KS; j++) {
                const float gj  = g[j];
                const float tsn = sv[j + 1] * sv[j + 1];
                const float tdn = dv[j + 1] * dv[j + 1];
                h0a = fmaf(gj, sv[j],     h0a); h0b = fmaf(gj, sv[j + 1], h0b);
                h1a = fmaf(gj, dv[j],     h1a); h1b = fmaf(gj, dv[j + 1], h1b);
                h2a = fmaf(gj, ts,        h2a); h2b = fmaf(gj, tsn,       h2b);
                h3a = fmaf(gj, td,        h3a); h3b = fmaf(gj, tdn,       h3b);
                ts = tsn; td = tdn;
            }

            // ---- vertical accumulate into rotating slots (slot is compile-time) ----
            #pragma unroll
            for (int i = 0; i < KS; i++) {
                const int slot = (rr - i + KS) % KS;
                const float gi = g[i];
                acc[0][0][slot] = fmaf(gi, h0a, acc[0][0][slot]);
                acc[0][1][slot] = fmaf(gi, h0b, acc[0][1][slot]);
                acc[1][0][slot] = fmaf(gi, h1a, acc[1][0][slot]);
                acc[1][1][slot] = fmaf(gi, h1b, acc[1][1][slot]);
                acc[2][0][slot] = fmaf(gi, h2a, acc[2][0][slot]);
                acc[2][1][slot] = fmaf(gi, h2b, acc[2][1][slot]);
                acc[3][0][slot] = fmaf(gi, h3a, acc[3][0][slot]);
                acc[3][1][slot] = fmaf(gi, h3b, acc[3][1][slot]);
            }

            // ---- emit completed output row jloc = r-10 (slot (rr+1)%11) ----
            const int es   = (rr + 1) % KS;
            const int jloc = r - (KS - 1);
            if (jloc >= 0 && (row0 + jloc) < OUTD) {
                #pragma unroll
                for (int c = 0; c < 2; c++) {
                    if (c0 + c < OUTD) {
                        const float ms = acc[0][c][es], md = acc[1][c][es];
                        const float Ss = acc[2][c][es], Sd = acc[3][c][es];
                        const float a = ms * ms, b = md * md;
                        const float P = a - b;        // 4 mu_x mu_y
                        const float Q = a + b;        // 2(mu_x^2 + mu_y^2)
                        const float U = Ss - Sd;      // 4 conv(xy)
                        const float V = Ss + Sd;      // 2(conv x^2 + conv y^2)
                        const float num = (P + C1x2) * ((U - P) + C2x2);
                        const float den = (Q + C1x2) * ((V - Q) + C2x2);
                        float rc = __builtin_amdgcn_rcpf(den);
                        rc = rc * fmaf(-den, rc, 2.0f);   // one NR step: ~0.5 ulp
                        ssum = fmaf(num, rc, ssum);
                    }
                }
            }
            // reset emitted slots for reuse (must happen every row, valid or not)
            #pragma unroll
            for (int q = 0; q < 4; q++) { acc[q][0][es] = 0.f; acc[q][1][es] = 0.f; }

            __syncthreads();
        }
    }

    // block reduction: wave shuffle then cross-wave via LDS
    #pragma unroll
    for (int off = 32; off > 0; off >>= 1)
        ssum += __shfl_down(ssum, off);
    const int wave = tid >> 6;
    if ((tid & 63) == 0) wsums[wave] = ssum;
    __syncthreads();
    if (tid == 0) {
        float s = wsums[0] + wsums[1] + wsums[2] + wsums[3];
        atomicAdd(acc_out, (double)s);
    }
}

__global__ void ssim_finalize(const double* __restrict__ acc, float* __restrict__ out)
{
    // total outputs: 96 * 502 * 502 = 24,192,384
    out[0] = (float)(acc[0] * (1.0 / 24192384.0));
}

extern "C" void kernel_launch(void* const* d_in, const int* in_sizes, int n_in,
                              void* d_out, int out_size, void* d_ws, size_t ws_size,
                              hipStream_t stream)
{
    const float* x   = (const float*)d_in[0];
    const float* y   = (const float*)d_in[1];
    const float* win = (const float*)d_in[2];
    float* out = (float*)d_out;
    double* acc = (double*)d_ws;

    hipMemsetAsync(acc, 0, sizeof(double), stream);
    ssim_main<<<dim3(NIMG * NB), dim3(256), 0, stream>>>(x, y, win, acc);
    ssim_finalize<<<dim3(1), dim3(1), 0, stream>>>(acc, out);
}

// Round 2
// 282.809 us; speedup vs baseline: 1.4245x; 1.4245x over previous
//
#include <hip/hip_runtime.h>

#define KS    11
#define HH    512
#define WW    512
#define OUTD  502          // HH - KS + 1
#define OH    33           // output rows emitted per band
#define ROWS  44           // OH + KS = 4*11 staged rows (multiple of KS)
#define NB    16           // 16*33 = 528 >= 502; 96*16 = 1536 blocks = 3 full rounds @ 2/CU
#define NIMG  96           // N*C = 32*3
#define PADW  524          // 512 + pad for horizontal reads up to c+11

// Streaming separable SSIM, sum/difference form:
//  s = x+y, d = x-y staged in LDS (double-buffered, 1 barrier/row).
//  Only 4 convolved quantities {s, d, s^2, d^2} instead of 5:
//    4 mu_x mu_y        = ms^2 - md^2
//    2(mu_x^2+mu_y^2)   = ms^2 + md^2
//    4 conv(xy)         = Sss - Sdd
//    2(conv x^2 + y^2)  = Sss + Sdd
//  Factors of 2/4 cancel against doubled constants (verified absmax 0.0 in R1).
//  launch_bounds(256,2): R1 proved a 3-wave cap causes catastrophic scratch
//  spill (WRITE_SIZE 184MB, VALUBusy 29%); 2 waves/SIMD is spill-free.
__global__ __launch_bounds__(256, 2)
void ssim_main(const float* __restrict__ xg, const float* __restrict__ yg,
               const float* __restrict__ win, double* __restrict__ acc_out)
{
    __shared__ float shs[2][PADW];   // s = x+y
    __shared__ float shd[2][PADW];   // d = x-y
    __shared__ float wsums[4];

    const int tid  = threadIdx.x;
    const int img  = blockIdx.x % NIMG;
    const int band = blockIdx.x / NIMG;
    const int row0 = band * OH;
    const int c0   = 2 * tid;

    // Recover 1D gaussian from the (normalized, rank-1) 2D window: row sums.
    // Symmetric kernel: store g[0..5] only, G(j) folds at compile time.
    float g[6];
    #pragma unroll
    for (int i = 0; i < 6; i++) {
        float s = 0.f;
        #pragma unroll
        for (int j = 0; j < KS; j++) s += win[i * KS + j];
        g[i] = s;
    }
#define G(j) g[(j) <= 5 ? (j) : 10 - (j)]

    // Zero the LDS pad (cols 512..PADW-1); only feeds invalid outputs but must be finite.
    if (tid < (PADW - WW)) {
        shs[0][WW + tid] = 0.f; shs[1][WW + tid] = 0.f;
        shd[0][WW + tid] = 0.f; shd[1][WW + tid] = 0.f;
    }

    const float* xi = xg + (size_t)img * HH * WW;
    const float* yi = yg + (size_t)img * HH * WW;

    // rotating vertical accumulators [quantity][col][slot]; q: 0=s 1=d 2=s2 3=d2
    // Lifecycle: slot k is OVERWRITTEN (mul, i==0) at the row after it is
    // emitted, then accumulated 10 more rows, then emitted. No reset pass.
    float acc[4][2][KS];
    #pragma unroll
    for (int q = 0; q < 4; q++)
        #pragma unroll
        for (int c = 0; c < 2; c++)
            #pragma unroll
            for (int s = 0; s < KS; s++) acc[q][c][s] = 0.f;

    float ssum = 0.f;

    const float C1x2 = 0.0002f;  // 2*(0.01)^2
    const float C2x2 = 0.0018f;  // 2*(0.03)^2

    // prologue: row 0 -> buf0 (as s,d), prefetch row 1 into regs (as s,d)
    float2 pfs, pfd;
    {
        int gr = row0; if (gr > HH - 1) gr = HH - 1;
        float2 ax = *(const float2*)&xi[(size_t)gr * WW + c0];
        float2 ay = *(const float2*)&yi[(size_t)gr * WW + c0];
        shs[0][c0] = ax.x + ay.x; shs[0][c0 + 1] = ax.y + ay.y;
        shd[0][c0] = ax.x - ay.x; shd[0][c0 + 1] = ax.y - ay.y;
        gr = row0 + 1; if (gr > HH - 1) gr = HH - 1;
        ax = *(const float2*)&xi[(size_t)gr * WW + c0];
        ay = *(const float2*)&yi[(size_t)gr * WW + c0];
        pfs = make_float2(ax.x + ay.x, ax.y + ay.y);
        pfd = make_float2(ax.x - ay.x, ax.y - ay.y);
    }
    __syncthreads();

    #pragma unroll 1
    for (int rb = 0; rb < ROWS / KS; rb++) {
        #pragma unroll
        for (int rr = 0; rr < KS; rr++) {
            const int r = rb * KS + rr;

            // ---- read 12 s / 12 d for this row from LDS (b64, contiguous) ----
            const float* sb = shs[r & 1];
            const float* db = shd[r & 1];
            float sv[12], dv[12];
            #pragma unroll
            for (int k = 0; k < 6; k++) {
                float2 a = *(const float2*)&sb[c0 + 2 * k];
                float2 b = *(const float2*)&db[c0 + 2 * k];
                sv[2 * k] = a.x; sv[2 * k + 1] = a.y;
                dv[2 * k] = b.x; dv[2 * k + 1] = b.y;
            }

            // ---- write prefetched row r+1 into the other buffer; prefetch r+2 ----
            if (r + 1 < ROWS) {
                float* sw = shs[(r + 1) & 1];
                float* dw = shd[(r + 1) & 1];
                sw[c0] = pfs.x; sw[c0 + 1] = pfs.y;
                dw[c0] = pfd.x; dw[c0 + 1] = pfd.y;
            }
            if (r + 2 < ROWS) {
                int gr = row0 + r + 2; if (gr > HH - 1) gr = HH - 1;
                float2 ax = *(const float2*)&xi[(size_t)gr * WW + c0];
                float2 ay = *(const float2*)&yi[(size_t)gr * WW + c0];
                pfs = make_float2(ax.x + ay.x, ax.y + ay.y);
                pfd = make_float2(ax.x - ay.x, ax.y - ay.y);
            }

            // ---- horizontal 11-tap conv, 2 cols x 4 quantities ----
            // squares via rolling pair (ts,td): only 2 transient regs live.
            float h0a = 0.f, h0b = 0.f, h1a = 0.f, h1b = 0.f;
            float h2a = 0.f, h2b = 0.f, h3a = 0.f, h3b = 0.f;
            float ts = sv[0] * sv[0];
            float td = dv[0] * dv[0];
            #pragma unroll
            for (int j = 0; j < KS; j++) {
                const float gj  = G(j);
                const float tsn = sv[j + 1] * sv[j + 1];
                const float tdn = dv[j + 1] * dv[j + 1];
                h0a = fmaf(gj, sv[j],     h0a); h0b = fmaf(gj, sv[j + 1], h0b);
                h1a = fmaf(gj, dv[j],     h1a); h1b = fmaf(gj, dv[j + 1], h1b);
                h2a = fmaf(gj, ts,        h2a); h2b = fmaf(gj, tsn,       h2b);
                h3a = fmaf(gj, td,        h3a); h3b = fmaf(gj, td = tdn,  h3b);
                ts = tsn;
            }

            // ---- vertical accumulate into rotating slots (slot is compile-time) ----
            // i == 0 targets slot rr, which was emitted last row: OVERWRITE (mul).
            {
                const float g0 = G(0);
                acc[0][0][rr] = g0 * h0a; acc[0][1][rr] = g0 * h0b;
                acc[1][0][rr] = g0 * h1a; acc[1][1][rr] = g0 * h1b;
                acc[2][0][rr] = g0 * h2a; acc[2][1][rr] = g0 * h2b;
                acc[3][0][rr] = g0 * h3a; acc[3][1][rr] = g0 * h3b;
            }
            #pragma unroll
            for (int i = 1; i < KS; i++) {
                const int slot = (rr - i + KS) % KS;
                const float gi = G(i);
                acc[0][0][slot] = fmaf(gi, h0a, acc[0][0][slot]);
                acc[0][1][slot] = fmaf(gi, h0b, acc[0][1][slot]);
                acc[1][0][slot] = fmaf(gi, h1a, acc[1][0][slot]);
                acc[1][1][slot] = fmaf(gi, h1b, acc[1][1][slot]);
                acc[2][0][slot] = fmaf(gi, h2a, acc[2][0][slot]);
                acc[2][1][slot] = fmaf(gi, h2b, acc[2][1][slot]);
                acc[3][0][slot] = fmaf(gi, h3a, acc[3][0][slot]);
                acc[3][1][slot] = fmaf(gi, h3b, acc[3][1][slot]);
            }

            // ---- emit completed output row jloc = r-10 (slot (rr+1)%11) ----
            // jloc < OH gate: row OH of this band is row 0 of the next band.
            const int es   = (rr + 1) % KS;
            const int jloc = r - (KS - 1);
            if (jloc >= 0 && jloc < OH && (row0 + jloc) < OUTD) {
                #pragma unroll
                for (int c = 0; c < 2; c++) {
                    if (c0 + c < OUTD) {
                        const float ms = acc[0][c][es], md = acc[1][c][es];
                        const float Ss = acc[2][c][es], Sd = acc[3][c][es];
                        const float a = ms * ms, b = md * md;
                        const float P = a - b;        // 4 mu_x mu_y
                        const float Q = a + b;        // 2(mu_x^2 + mu_y^2)
                        const float U = Ss - Sd;      // 4 conv(xy)
                        const float V = Ss + Sd;      // 2(conv x^2 + conv y^2)
                        const float num = (P + C1x2) * ((U - P) + C2x2);
                        const float den = (Q + C1x2) * ((V - Q) + C2x2);
                        float rc = __builtin_amdgcn_rcpf(den);
                        rc = rc * fmaf(-den, rc, 2.0f);   // one NR step: ~0.5 ulp
                        ssum = fmaf(num, rc, ssum);
                    }
                }
            }

            __syncthreads();
        }
    }

    // block reduction: wave shuffle then cross-wave via LDS
    #pragma unroll
    for (int off = 32; off > 0; off >>= 1)
        ssum += __shfl_down(ssum, off);
    const int wave = tid >> 6;
    if ((tid & 63) == 0) wsums[wave] = ssum;
    __syncthreads();
    if (tid == 0) {
        float s = wsums[0] + wsums[1] + wsums[2] + wsums[3];
        atomicAdd(acc_out, (double)s);
    }
}

__global__ void ssim_finalize(const double* __restrict__ acc, float* __restrict__ out)
{
    // total outputs: 96 * 502 * 502 = 24,192,384
    out[0] = (float)(acc[0] * (1.0 / 24192384.0));
}

extern "C" void kernel_launch(void* const* d_in, const int* in_sizes, int n_in,
                              void* d_out, int out_size, void* d_ws, size_t ws_size,
                              hipStream_t stream)
{
    const float* x   = (const float*)d_in[0];
    const float* y   = (const float*)d_in[1];
    const float* win = (const float*)d_in[2];
    float* out = (float*)d_out;
    double* acc = (double*)d_ws;

    hipMemsetAsync(acc, 0, sizeof(double), stream);
    ssim_main<<<dim3(NIMG * NB), dim3(256), 0, stream>>>(x, y, win, acc);
    ssim_finalize<<<dim3(1), dim3(1), 0, stream>>>(acc, out);
}